// Round 21
// baseline (119.815 us; speedup 1.0000x reference)
//
#include <hip/hip_runtime.h>

#define NPTS    65536
#define DIM     128
#define KCODES  1024
#define BM      64       // points per argmin block (grid 1024 -> 4 blocks/CU)
#define TILE_C  64       // codes per LDS tile (double-buffered 2x16 KB)
#define NTHR    256      // 4 waves; each wave owns 16 points
#define NTILE   (KCODES / TILE_C)   // 16

typedef _Float16 f16x8 __attribute__((ext_vector_type(8)));
typedef float    f32x4 __attribute__((ext_vector_type(4)));

__device__ __forceinline__ void gload_lds16(const void* g, void* l) {
    __builtin_amdgcn_global_load_lds(
        (const __attribute__((address_space(1))) void*)g,
        (__attribute__((address_space(3))) void*)l, 16, 0, 0);
}

// ---------------- Kernel P: pack codebook -> fp16 frag-order + halfnorm(rounded)
//                  + init acc (= 0.8*ema_embed, i.e. out2) + zero ghist ---------
// 64 blocks x 256. g in 0..16383: tc=g>>10 (tile of 64 codes), f=(g>>6)&15,
// l=g&63; f = nt*4+akk ; l = hg*16+n ; code c = tc*64+nt*16+n ; d0 = akk*32+hg*8.
__global__ __launch_bounds__(256)
void pack_kernel(const float* __restrict__ embed, _Float16* __restrict__ ebf,
                 int* __restrict__ ghist, const float* __restrict__ ema_embed,
                 float* __restrict__ acc, float* __restrict__ hn)
{
    __shared__ float partial[256];
    const int t = threadIdx.x;
    const int b = blockIdx.x;
    const int g = b * 256 + t;                       // 0..16383
    if (g < KCODES) ghist[g] = 0;
    {   // init acc = 0.8 * ema_embed (2 float4s per thread = 32768 total)
        float4 e0 = reinterpret_cast<const float4*>(ema_embed)[g];
        float4 e1 = reinterpret_cast<const float4*>(ema_embed)[g + 16384];
        reinterpret_cast<float4*>(acc)[g] =
            (float4){0.8f * e0.x, 0.8f * e0.y, 0.8f * e0.z, 0.8f * e0.w};
        reinterpret_cast<float4*>(acc)[g + 16384] =
            (float4){0.8f * e1.x, 0.8f * e1.y, 0.8f * e1.z, 0.8f * e1.w};
    }

    const int tc  = g >> 10;
    const int f   = (g >> 6) & 15;
    const int l   = g & 63;
    const int nt  = f >> 2;
    const int akk = f & 3;
    const int hg  = l >> 4;
    const int n   = l & 15;
    const int c   = tc * TILE_C + nt * 16 + n;
    const int d0  = akk * 32 + hg * 8;
    const float* src = embed + (long)c * DIM + d0;
    float4 v0 = *reinterpret_cast<const float4*>(src);
    float4 v1 = *reinterpret_cast<const float4*>(src + 4);
    float vv[8] = {v0.x, v0.y, v0.z, v0.w, v1.x, v1.y, v1.z, v1.w};
    f16x8 out;
    float ss = 0.f;
    #pragma unroll
    for (int j = 0; j < 8; ++j) {
        _Float16 h = (_Float16)vv[j];                // RNE
        out[j] = h;
        float r = (float)h;                          // halfnorm from ROUNDED values
        ss += r * r;
    }
    *reinterpret_cast<f16x8*>(ebf + (long)g * 8) = out;

    // block b holds 16 complete code rows (tc=b>>2, nt=b&3)
    partial[t] = ss;
    __syncthreads();
    if (t < 16) {
        float s = 0.f;
        #pragma unroll
        for (int k = 0; k < 16; ++k) s += partial[t + k * 16];
        hn[(b >> 2) * TILE_C + (b & 3) * 16 + t] = 0.5f * s;
    }
}

// ---------------- Kernel 1: MFMA fp16 argmin over FULL codebook ----------------
// grid 1024 (BM=64). Fused: quantize + histogram + DIRECT atomic segment-sum.
__global__ __launch_bounds__(NTHR, 4)
void argmin_kernel(const float* __restrict__ x, const _Float16* __restrict__ ebf,
                   const float* __restrict__ halfnorm, const float* __restrict__ embed,
                   float* __restrict__ quant, int* __restrict__ ghist,
                   float* __restrict__ acc)
{
    __shared__ _Float16 es[2][8192];    // 2 x 16 KB double-buffered tile
    __shared__ int      hist[KCODES];   // 4 KB
    __shared__ int      bidx[BM];

    const int t    = threadIdx.x;
    const int lane = t & 63;
    const int w    = t >> 6;           // wave 0..3, owns 16 points
    const int r16  = lane & 15;
    const int h4   = lane >> 4;
    const long xbase = (long)blockIdx.x * BM * DIM;
    const int  wp    = w * 16;

    for (int i = t; i < KCODES; i += NTHR) hist[i] = 0;

    // ---- A fragments: row (wp + r16), fp16 ----
    f16x8 a[4];
    {
        const long prow = xbase + (long)(wp + r16) * DIM;
        #pragma unroll
        for (int akk = 0; akk < 4; ++akk) {
            const float* s = x + prow + akk * 32 + h4 * 8;
            float4 u0 = *reinterpret_cast<const float4*>(s);
            float4 u1 = *reinterpret_cast<const float4*>(s + 4);
            float vv[8] = {u0.x, u0.y, u0.z, u0.w, u1.x, u1.y, u1.z, u1.w};
            #pragma unroll
            for (int j = 0; j < 8; ++j) a[akk][j] = (_Float16)vv[j];
        }
    }

    // ---- prologue: stage tile 0 (wave w loads frags w*4..w*4+3, 1 KB each) ----
    #pragma unroll
    for (int i = 0; i < 4; ++i) {
        const int f = w * 4 + i;
        gload_lds16(ebf + (long)f * 512 + lane * 8, &es[0][f * 512]);
    }
    float hnv_cur[4], hnv_nxt[4];
    #pragma unroll
    for (int nt = 0; nt < 4; ++nt) hnv_cur[nt] = halfnorm[nt * 16 + r16];
    __syncthreads();   // tile 0 resident; hist zeroed

    float bestv[4];
    int   besti[4];
    #pragma unroll
    for (int s = 0; s < 4; ++s) { bestv[s] = -1e30f; besti[s] = 0; }

    #pragma unroll 1
    for (int tile = 0; tile < NTILE; ++tile) {
        // issue next tile's stage + next halfnorms (latency hides under MFMA)
        if (tile + 1 < NTILE) {
            const long gbase = (long)(tile + 1) * 8192;
            #pragma unroll
            for (int i = 0; i < 4; ++i) {
                const int f = w * 4 + i;
                gload_lds16(ebf + gbase + f * 512 + lane * 8, &es[(tile + 1) & 1][f * 512]);
            }
            #pragma unroll
            for (int nt = 0; nt < 4; ++nt)
                hnv_nxt[nt] = halfnorm[(tile + 1) * TILE_C + nt * 16 + r16];
        }

        f32x4 C[4];
        #pragma unroll
        for (int nt = 0; nt < 4; ++nt) C[nt] = (f32x4){0.f, 0.f, 0.f, 0.f};

        #pragma unroll
        for (int akk = 0; akk < 4; ++akk) {
            #pragma unroll
            for (int nt = 0; nt < 4; ++nt) {
                f16x8 B = *reinterpret_cast<const f16x8*>(
                    &es[tile & 1][(nt * 4 + akk) * 512 + lane * 8]);
                C[nt] = __builtin_amdgcn_mfma_f32_16x16x32_f16(a[akk], B, C[nt], 0, 0, 0);
            }
        }

        // ---- scores + running argmax (codes ascending: tile asc, nt asc) ----
        #pragma unroll
        for (int nt = 0; nt < 4; ++nt) {
            const int c = tile * TILE_C + nt * 16 + r16;
            #pragma unroll
            for (int reg = 0; reg < 4; ++reg) {
                float sc = C[nt][reg] - hnv_cur[nt];
                if (sc > bestv[reg]) { bestv[reg] = sc; besti[reg] = c; }
            }
        }
        #pragma unroll
        for (int nt = 0; nt < 4; ++nt) hnv_cur[nt] = hnv_nxt[nt];
        __syncthreads();   // next tile resident; current tile readers done
    }

    // ---- butterfly reduce across 16 columns, tie -> smaller idx ----
    #pragma unroll
    for (int s = 0; s < 4; ++s) {
        float v = bestv[s];
        int   i = besti[s];
        #pragma unroll
        for (int off = 1; off < 16; off <<= 1) {
            float ov = __shfl_xor(v, off);
            int   oi = __shfl_xor(i, off);
            if (ov > v || (ov == v && oi < i)) { v = ov; i = oi; }
        }
        bestv[s] = v; besti[s] = i;
    }
    if (r16 == 0) {
        #pragma unroll
        for (int s = 0; s < 4; ++s) {
            int p = wp + h4 * 4 + s;     // point = row (h4*4 + reg)
            bidx[p] = besti[s];
        }
    }
    __syncthreads();

    // ---- LDS histogram of this block's 64 assignments ----
    if (t < BM) atomicAdd(&hist[bidx[t]], 1);

    // ---- quantize: lane-contiguous gather-copy of embed[best] ----
    float4* dst = reinterpret_cast<float4*>(quant + xbase);
    #pragma unroll
    for (int i = 0; i < 8; ++i) {
        int idx = i * NTHR + t;          // 0..2047
        int p   = idx >> 5;
        int q   = idx & 31;
        int c   = bidx[p];
        dst[idx] = reinterpret_cast<const float4*>(embed + (long)c * DIM)[q];
    }

    __syncthreads();
    for (int i = t; i < KCODES; i += NTHR)
        if (hist[i]) atomicAdd(&ghist[i], hist[i]);

    // ---- direct segment-sum: acc[code] += 0.2 * x[p]  (x rows L2-warm) ----
    #pragma unroll 4
    for (int rep = 0; rep < BM * DIM / NTHR; ++rep) {   // 32 reps
        const int flat = rep * NTHR + t;                // 0..8191
        const int p    = flat >> 7;
        const int d    = flat & 127;
        atomicAdd(&acc[(long)bidx[p] * DIM + d],
                  0.2f * x[xbase + (long)p * DIM + d]);
    }
}

// ---------------- Kernel F: ema_num_new + embed_new = acc / en -----------------
__global__ __launch_bounds__(256)
void final_kernel(const float* __restrict__ acc, const int* __restrict__ ghist,
                  const float* __restrict__ ema_num, float* __restrict__ ema_num_new,
                  float* __restrict__ embed_new)
{
    const int g = blockIdx.x * 256 + threadIdx.x;   // 0..32767 float4s
    const int c = g >> 5;                           // 32 float4s per code row
    float4 v = reinterpret_cast<const float4*>(acc)[g];
    const float en = ema_num[c] * 0.8f + 0.2f * (float)ghist[c];
    if ((g & 31) == 0) ema_num_new[c] = en;
    float4 o = {v.x / en, v.y / en, v.z / en, v.w / en};
    reinterpret_cast<float4*>(embed_new)[g] = o;
}

extern "C" void kernel_launch(void* const* d_in, const int* in_sizes, int n_in,
                              void* d_out, int out_size, void* d_ws, size_t ws_size,
                              hipStream_t stream)
{
    const float* x         = (const float*)d_in[0];
    const float* embed     = (const float*)d_in[1];
    const float* ema_embed = (const float*)d_in[2];
    const float* ema_num   = (const float*)d_in[3];

    float* out0 = (float*)d_out;            // quantize      (16*4096*128)
    float* out1 = out0 + 8388608;           // embed_new     (1024*128)
    float* out2 = out1 + 131072;            // ema_embed_new (1024*128)
    float* out3 = out2 + 131072;            // ema_num_new   (1024)

    char* ws = (char*)d_ws;
    float*    hn    = (float*)ws;                   // 4 KB
    _Float16* ebf   = (_Float16*)(ws + 4096);       // 256 KB
    int*      ghist = (int*)(ws + 266240);          // 4 KB

    pack_kernel<<<64, 256, 0, stream>>>(embed, ebf, ghist, ema_embed, out2, hn);
    argmin_kernel<<<NPTS / BM, NTHR, 0, stream>>>(x, ebf, hn, embed, out0, ghist, out2);
    final_kernel<<<128, 256, 0, stream>>>(out2, ghist, ema_num, out3, out1);
}